// Round 18
// baseline (211.706 us; speedup 1.0000x reference)
//
#include <hip/hip_runtime.h>
#include <float.h>
#include <math.h>

#define ZM 8192
#define CN 16384
#define KD 256
#define HWN 1024
#define ZSTRIDE 262144
#define NCHA 16     // 1024 codes per chunk, running top-2 per chunk

typedef short  s16x8  __attribute__((ext_vector_type(8)));
typedef float  f32x4  __attribute__((ext_vector_type(4)));

__device__ inline void gld_lds16(const void* g, void* l) {
    __builtin_amdgcn_global_load_lds((__attribute__((address_space(1))) void*)(g),
                                     (__attribute__((address_space(3))) void*)(l), 16, 0, 0);
}

// ---------------- fused cb stats + bf16 prep (one cb read) ----------------

__global__ void cbprep_kernel(const float* __restrict__ cb, float* __restrict__ cbrinv,
                              float* __restrict__ cbsq, __bf16* __restrict__ Bh) {
    __shared__ float sm[4];
    __shared__ float rsh;
    int n = blockIdx.x;
    float v = cb[(size_t)n * KD + threadIdx.x];
    float s = v * v;
    #pragma unroll
    for (int m = 32; m; m >>= 1) s += __shfl_xor(s, m, 64);
    if ((threadIdx.x & 63) == 0) sm[threadIdx.x >> 6] = s;
    __syncthreads();
    if (threadIdx.x == 0) {
        float t = sm[0] + sm[1] + sm[2] + sm[3];
        float r = 1.0f / fmaxf(sqrtf(t), 1e-12f);
        cbrinv[n] = r;
        cbsq[n] = t * r * r;
        rsh = r;
    }
    __syncthreads();
    Bh[(size_t)n * KD + threadIdx.x] = (__bf16)(v * rsh);
}

// ---------------- z transpose: bf16 Ah + f32 Zt ----------------

__global__ void prep_a_kernel(const float* __restrict__ z, __bf16* __restrict__ Ah,
                              float* __restrict__ Zt) {
    __shared__ float tile[64][65];
    int hw0 = blockIdx.x * 64, c0 = blockIdx.y * 64, b = blockIdx.z;
    int tid = threadIdx.x;
    #pragma unroll
    for (int i = 0; i < 16; ++i) {
        int lin = i * 256 + tid;
        int cl = lin >> 6, hwl = lin & 63;
        tile[cl][hwl] = z[(size_t)b * ZSTRIDE + (size_t)(c0 + cl) * HWN + hw0 + hwl];
    }
    __syncthreads();
    #pragma unroll
    for (int i = 0; i < 16; ++i) {
        int lin = i * 256 + tid;
        int hwl = lin >> 6, cl = lin & 63;
        float v = tile[cl][hwl];
        size_t o = (size_t)(b * 1024 + hw0 + hwl) * KD + c0 + cl;
        Ah[o] = (__bf16)v;
        Zt[o] = v;
    }
}

// ---------------- bf16 MFMA GEMM: A->VGPR direct, B->LDS (swizzled), bias-32 fold --
// A fragment = 16 contiguous bytes of row-major A -> plain global_load_dwordx4,
// double-buffered in named aE/aN sets (no LDS round-trip for A). B stays
// gld_lds-staged + XOR-swizzle (0 conflicts). Unroll-by-4: buf index, k0, and
// A-set all compile-time static. Counted vmcnt(12) = this step's 4 B-glds +
// 8 A-loads; drains all older ops before the barrier. acc init/reset = 32.0f
// => all scores positive => uint order == float order (no sign transform).

__global__ __launch_bounds__(256, 2) void gemm_top2_kernel(
    const __bf16* __restrict__ A, const __bf16* __restrict__ B,
    uint2* __restrict__ part)
{
    __shared__ __bf16 sB[2][128 * 64];   // 16 KB per buf
    __shared__ uint2 sred[2][128];

    const int tid = threadIdx.x;
    const int l = tid & 63;
    const int wid = tid >> 6;
    const int wm = (wid >> 1) * 64, wn = (wid & 1) * 64;
    const int m0 = blockIdx.x * 128;
    const int chunk = blockIdx.y;
    const int fr = l & 15;
    const int fkg = l >> 4;              // k-granule subindex 0..3

    // B staging: per-lane global offsets (swizzled source) + LDS dests, once
    int laneOff[4], dstOff[4];
    #pragma unroll
    for (int j = 0; j < 4; ++j) {
        int sl = j * 256 + tid;
        int r = sl >> 3, c = sl & 7;
        int cs = c ^ (r & 7);
        laneOff[j] = r * KD + cs * 8;
        dstOff[j] = sl * 8;
    }
    const __bf16* Btl[4];
    #pragma unroll
    for (int j = 0; j < 4; ++j)
        Btl[j] = B + (size_t)chunk * 1024 * KD + laneOff[j];

    // B frag base (element offset in one 16KB buffer); kh flips elem bit 5
    const int cg0 = fkg ^ (fr & 7);
    const int fB0 = (wn + fr) * 64 + cg0 * 8;

    // A frag pointers: 4 rows (ti), k advances via static offsets
    const __bf16* Ap[4];
    #pragma unroll
    for (int ti = 0; ti < 4; ++ti)
        Ap[ti] = A + (size_t)(m0 + wm + ti * 16 + fr) * KD + fkg * 8;

    unsigned khi[16], klo[16];
    #pragma unroll
    for (int sx = 0; sx < 16; ++sx) { khi[sx] = 0u; klo[sx] = 0u; }

    unsigned nkey[4];
    #pragma unroll
    for (int tj = 0; tj < 4; ++tj) nkey[tj] = (unsigned)(wn + tj * 16 + fr);

    f32x4 acc[4][4];
    #pragma unroll
    for (int ti = 0; ti < 4; ++ti)
        #pragma unroll
        for (int tj = 0; tj < 4; ++tj) acc[ti][tj] = (f32x4){32.f, 32.f, 32.f, 32.f};

    s16x8 aE[8], aN[8];

    #define STAGE_B(buf, k0e)                                                     \
        _Pragma("unroll")                                                         \
        for (int j = 0; j < 4; ++j)                                               \
            gld_lds16(Btl[j] + (k0e), &sB[buf][dstOff[j]]);

    #define LOAD_A(aset, k0e)                                                     \
        _Pragma("unroll")                                                         \
        for (int ti = 0; ti < 4; ++ti) {                                          \
            aset[ti * 2 + 0] = *(const s16x8*)(Ap[ti] + (k0e));                   \
            aset[ti * 2 + 1] = *(const s16x8*)(Ap[ti] + (k0e) + 32);              \
        }

    #define COMPUTE(buf, aset)                                                    \
        _Pragma("unroll")                                                         \
        for (int kh = 0; kh < 2; ++kh) {                                          \
            const __bf16* fB = &sB[buf][fB0 ^ (kh * 32)];                         \
            s16x8 bhf[4];                                                         \
            _Pragma("unroll")                                                     \
            for (int tj = 0; tj < 4; ++tj)                                        \
                bhf[tj] = *(const s16x8*)(fB + tj * 1024);                        \
            _Pragma("unroll")                                                     \
            for (int ti = 0; ti < 4; ++ti) {                                      \
                s16x8 ahf = aset[ti * 2 + kh];                                    \
                _Pragma("unroll")                                                 \
                for (int tj = 0; tj < 4; ++tj)                                    \
                    acc[ti][tj] = __builtin_amdgcn_mfma_f32_16x16x32_bf16(        \
                        ahf, bhf[tj], acc[ti][tj], 0, 0, 0);                      \
            }                                                                     \
        }

    #define FOLD()                                                                \
        _Pragma("unroll")                                                         \
        for (int sx = 0; sx < 16; ++sx) {                                         \
            const int ti_ = sx >> 2, r_ = sx & 3;                                 \
            _Pragma("unroll")                                                     \
            for (int tj = 0; tj < 4; ++tj) {                                      \
                unsigned u = __float_as_uint(acc[ti_][tj][r_]);                   \
                unsigned key = (u & 0xFFFFFC00u) | nkey[tj];                      \
                unsigned h = khi[sx];                                             \
                unsigned mn = min(h, key);                                        \
                khi[sx] = max(h, key);                                            \
                klo[sx] = max(klo[sx], mn);                                       \
                acc[ti_][tj][r_] = 32.f;                                          \
            }                                                                     \
        }                                                                         \
        _Pragma("unroll")                                                         \
        for (int tj = 0; tj < 4; ++tj) nkey[tj] += 128u;

    // prologue: step 0 (k0=0, buf0)
    STAGE_B(0, 0);
    LOAD_A(aE, 0);

    for (int sp = 0; sp < 32; sp += 4) {
        // p=0: step sp (buf0, aE, k0=0); stage sp+1 (buf1, k0=64)
        STAGE_B(1, 64); LOAD_A(aN, 64);
        asm volatile("s_waitcnt vmcnt(12)" ::: "memory");
        __builtin_amdgcn_s_barrier();
        COMPUTE(0, aE);
        __builtin_amdgcn_s_barrier();

        // p=1: step sp+1 (buf1, aN, k0=64); stage sp+2 (buf0, k0=128)
        STAGE_B(0, 128); LOAD_A(aE, 128);
        asm volatile("s_waitcnt vmcnt(12)" ::: "memory");
        __builtin_amdgcn_s_barrier();
        COMPUTE(1, aN);
        __builtin_amdgcn_s_barrier();

        // p=2: step sp+2 (buf0, aE, k0=128); stage sp+3 (buf1, k0=192)
        STAGE_B(1, 192); LOAD_A(aN, 192);
        asm volatile("s_waitcnt vmcnt(12)" ::: "memory");
        __builtin_amdgcn_s_barrier();
        COMPUTE(0, aE);
        __builtin_amdgcn_s_barrier();

        // p=3: step sp+3 (buf1, aN, k0=192); stage sp+4 (next t, buf0, k0=0)
        if (sp + 4 < 32) {
            #pragma unroll
            for (int j = 0; j < 4; ++j) Btl[j] += 128 * KD;
            STAGE_B(0, 0); LOAD_A(aE, 0);
            asm volatile("s_waitcnt vmcnt(12)" ::: "memory");
        } else {
            asm volatile("s_waitcnt vmcnt(0)" ::: "memory");
        }
        __builtin_amdgcn_s_barrier();
        COMPUTE(1, aN);
        FOLD();
        __builtin_amdgcn_s_barrier();
    }

    // 16-lane butterfly merge, then cross-wave merge via LDS
    #pragma unroll
    for (int sx = 0; sx < 16; ++sx) {
        unsigned h = khi[sx], lo_ = klo[sx];
        #pragma unroll
        for (int m = 1; m < 16; m <<= 1) {
            unsigned oh = (unsigned)__shfl_xor((int)h, m, 64);
            unsigned ol = (unsigned)__shfl_xor((int)lo_, m, 64);
            unsigned nh = max(h, oh);
            lo_ = max(min(h, oh), max(lo_, ol));
            h = nh;
        }
        if ((l & 15) == 0) {
            int rowlb = wm + (sx >> 2) * 16 + (l >> 4) * 4 + (sx & 3);
            sred[wn >> 6][rowlb] = make_uint2(h, lo_);
        }
    }
    __syncthreads();
    if (tid < 128) {
        uint2 pa = sred[0][tid], pb = sred[1][tid];
        unsigned h = max(pa.x, pb.x);
        unsigned lo_ = max(min(pa.x, pb.x), max(pa.y, pb.y));
        part[(size_t)(m0 + tid) * NCHA + chunk] = make_uint2(h, lo_);
    }
    #undef STAGE_B
    #undef LOAD_A
    #undef COMPUTE
    #undef FOLD
}

// ---------------- exact fp32 rescue over all 32 candidates/row ----------------
// zrinv recomputed with a bit-identical replication of R1's reduction tree.

__global__ void rescue_all_kernel(const float* __restrict__ Zt, const float* __restrict__ cb,
                                  const float* __restrict__ cbrinv, const float* __restrict__ cbsq,
                                  const uint2* __restrict__ part,
                                  int* __restrict__ ridx, float* __restrict__ out_idx) {
    int row = blockIdx.x;
    __shared__ float zrow[KD];
    int tid = threadIdx.x;   // 64 threads; lanes 32..63 duplicate slots 0..31
    ((float4*)zrow)[tid] = ((const float4*)(Zt + (size_t)row * KD))[tid];
    __syncthreads();

    float tot = 0.f;
    #pragma unroll
    for (int w = 0; w < 4; ++w) {
        float v = zrow[w * 64 + tid];
        float s = v * v;
        #pragma unroll
        for (int m = 32; m; m >>= 1) s += __shfl_xor(s, m, 64);
        tot += s;
    }
    float zrinv = 1.0f / fmaxf(sqrtf(tot), 1e-12f);

    int slot = tid & 31;
    uint2 p = part[(size_t)row * NCHA + (slot >> 1)];
    unsigned key = (slot & 1) ? p.y : p.x;
    int n = (slot >> 1) * 1024 + (int)(key & 1023u);
    float sc = cbrinv[n];
    const float4* c4 = (const float4*)(cb + (size_t)n * KD);
    const float4* z4 = (const float4*)zrow;
    float acc = 0.f;
    #pragma unroll 8
    for (int k = 0; k < KD / 4; ++k) {
        float4 cv = c4[k];
        float4 zv = z4[k];
        acc = fmaf(zv.x, cv.x * sc, acc);
        acc = fmaf(zv.y, cv.y * sc, acc);
        acc = fmaf(zv.z, cv.z * sc, acc);
        acc = fmaf(zv.w, cv.w * sc, acc);
    }
    float s = fmaf(zrinv, acc, -0.5f * cbsq[n]);
    #pragma unroll
    for (int m = 1; m < 32; m <<= 1) {
        float ov = __shfl_xor(s, m, 64); int on = __shfl_xor(n, m, 64);
        if (ov > s || (ov == s && on < n)) { s = ov; n = on; }
    }
    if (tid == 0) { ridx[row] = n; out_idx[row] = (float)n; }
}

// ---------------- gather + z_q output (coalesced via LDS transpose) + loss ----------

__global__ void finalize_kernel(const float* __restrict__ Zt, const float* __restrict__ cb,
                                const int* __restrict__ ridx,
                                float* __restrict__ zq_out, float* __restrict__ lpart) {
    __shared__ float zqt[64][257];
    __shared__ int idxs[64];
    __shared__ float sm[4];
    int b = blockIdx.x, hw0 = blockIdx.y * 64, tid = threadIdx.x;
    if (tid < 64) idxs[tid] = ridx[b * 1024 + hw0 + tid];
    __syncthreads();
    float dsum = 0.f;
    for (int i = 0; i < 64; ++i) {
        int row = b * 1024 + hw0 + i;
        float zt = Zt[(size_t)row * KD + tid];
        float zq = cb[(size_t)idxs[i] * KD + tid];
        float d = zq - zt;
        zqt[i][tid] = zt + d;
        dsum = fmaf(d, d, dsum);
    }
    #pragma unroll
    for (int m = 32; m; m >>= 1) dsum += __shfl_xor(dsum, m, 64);
    if ((tid & 63) == 0) sm[tid >> 6] = dsum;
    __syncthreads();
    if (tid == 0) lpart[blockIdx.x * 16 + blockIdx.y] = sm[0] + sm[1] + sm[2] + sm[3];
    for (int i = 0; i < 64; ++i) {
        int idx = i * 256 + tid;
        int c = idx >> 6, hwl = idx & 63;
        zq_out[(size_t)b * ZSTRIDE + (size_t)c * HWN + hw0 + hwl] = zqt[hwl][c];
    }
}

__global__ void loss_final_kernel(const float* __restrict__ lpart, float* __restrict__ out) {
    __shared__ float sm[4];
    float s = 0.0f;
    for (int i = threadIdx.x; i < 128; i += 256) s += lpart[i];
    #pragma unroll
    for (int m = 32; m; m >>= 1) s += __shfl_xor(s, m, 64);
    if ((threadIdx.x & 63) == 0) sm[threadIdx.x >> 6] = s;
    __syncthreads();
    if (threadIdx.x == 0) {
        float total = sm[0] + sm[1] + sm[2] + sm[3];
        float m = total * (1.0f / 2097152.0f);
        out[0] = fmaf(0.25f, m, m);
    }
}

// ---------------- launch ----------------

extern "C" void kernel_launch(void* const* d_in, const int* in_sizes, int n_in,
                              void* d_out, int out_size, void* d_ws, size_t ws_size,
                              hipStream_t stream) {
    const float* z  = (const float*)d_in[0];
    const float* cb = (const float*)d_in[1];
    float* out = (float*)d_out;

    float* ws = (float*)d_ws;
    float*  cbrinv = ws;                                 // 16384
    float*  cbsq   = cbrinv + CN;                        // 16384
    int*    ridx   = (int*)(cbsq + CN);                  // 8192
    float*  lpart  = (float*)(ridx + ZM);                // 8192 (128 used)
    uint2*  part   = (uint2*)(lpart + ZM);               // 1 MB (16B-aligned)
    __bf16* Ah     = (__bf16*)(part + (size_t)ZM * NCHA);// 4 MB
    __bf16* Bh     = Ah + (size_t)ZM * KD;               // 8 MB
    float*  Zt     = (float*)(Bh + (size_t)CN * KD);     // 8 MB  (total ~21.4 MB)

    float* out_loss = out;
    float* out_zq   = out + 1;
    float* out_idx  = out + 1 + (size_t)ZM * KD;

    cbprep_kernel<<<CN, 256, 0, stream>>>(cb, cbrinv, cbsq, Bh);
    prep_a_kernel<<<dim3(16, 4, 8), 256, 0, stream>>>(z, Ah, Zt);
    gemm_top2_kernel<<<dim3(64, 16), 256, 0, stream>>>(Ah, Bh, part);
    rescue_all_kernel<<<ZM, 64, 0, stream>>>(Zt, cb, cbrinv, cbsq, part, ridx, out_idx);
    finalize_kernel<<<dim3(8, 16), 256, 0, stream>>>(Zt, cb, ridx, out_zq, lpart);
    loss_final_kernel<<<1, 256, 0, stream>>>(lpart, out_loss);
}

// Round 19
// 184.638 us; speedup vs baseline: 1.1466x; 1.1466x over previous
//
#include <hip/hip_runtime.h>
#include <float.h>
#include <math.h>

#define ZM 8192
#define CN 16384
#define KD 256
#define HWN 1024
#define ZSTRIDE 262144
#define NCHA 16     // 1024 codes per chunk, running top-2 per chunk

typedef short  s16x8  __attribute__((ext_vector_type(8)));
typedef float  f32x4  __attribute__((ext_vector_type(4)));

__device__ inline void gld_lds16(const void* g, void* l) {
    __builtin_amdgcn_global_load_lds((__attribute__((address_space(1))) void*)(g),
                                     (__attribute__((address_space(3))) void*)(l), 16, 0, 0);
}

// ---------------- fused cb stats + bf16 prep (one cb read) ----------------

__global__ void cbprep_kernel(const float* __restrict__ cb, float* __restrict__ cbrinv,
                              float* __restrict__ cbsq, __bf16* __restrict__ Bh) {
    __shared__ float sm[4];
    __shared__ float rsh;
    int n = blockIdx.x;
    float v = cb[(size_t)n * KD + threadIdx.x];
    float s = v * v;
    #pragma unroll
    for (int m = 32; m; m >>= 1) s += __shfl_xor(s, m, 64);
    if ((threadIdx.x & 63) == 0) sm[threadIdx.x >> 6] = s;
    __syncthreads();
    if (threadIdx.x == 0) {
        float t = sm[0] + sm[1] + sm[2] + sm[3];
        float r = 1.0f / fmaxf(sqrtf(t), 1e-12f);
        cbrinv[n] = r;
        cbsq[n] = t * r * r;
        rsh = r;
    }
    __syncthreads();
    Bh[(size_t)n * KD + threadIdx.x] = (__bf16)(v * rsh);
}

// ---------------- z transpose: bf16 Ah + f32 Zt ----------------

__global__ void prep_a_kernel(const float* __restrict__ z, __bf16* __restrict__ Ah,
                              float* __restrict__ Zt) {
    __shared__ float tile[64][65];
    int hw0 = blockIdx.x * 64, c0 = blockIdx.y * 64, b = blockIdx.z;
    int tid = threadIdx.x;
    #pragma unroll
    for (int i = 0; i < 16; ++i) {
        int lin = i * 256 + tid;
        int cl = lin >> 6, hwl = lin & 63;
        tile[cl][hwl] = z[(size_t)b * ZSTRIDE + (size_t)(c0 + cl) * HWN + hw0 + hwl];
    }
    __syncthreads();
    #pragma unroll
    for (int i = 0; i < 16; ++i) {
        int lin = i * 256 + tid;
        int hwl = lin >> 6, cl = lin & 63;
        float v = tile[cl][hwl];
        size_t o = (size_t)(b * 1024 + hw0 + hwl) * KD + c0 + cl;
        Ah[o] = (__bf16)v;
        Zt[o] = v;
    }
}

// ---------------- bf16 MFMA GEMM: BK=64, swizzled gld_lds, counted-vmcnt ----
// (verbatim R17 — verified 106 µs, 0 bank conflicts, no spills)

__global__ __launch_bounds__(256, 2) void gemm_top2_kernel(
    const __bf16* __restrict__ A, const __bf16* __restrict__ B,
    uint2* __restrict__ part)
{
    __shared__ __bf16 sA[2][128 * 64];
    __shared__ __bf16 sB[2][128 * 64];
    __shared__ uint2 sred[2][128];

    const int tid = threadIdx.x;
    const int l = tid & 63;
    const int wid = tid >> 6;
    const int wm = (wid >> 1) * 64, wn = (wid & 1) * 64;
    const int m0 = blockIdx.x * 128;
    const int chunk = blockIdx.y;
    const int fr = l & 15;
    const int fkg = l >> 4;

    int laneOff[4], dstOff[4];
    #pragma unroll
    for (int j = 0; j < 4; ++j) {
        int sl = j * 256 + tid;
        int r = sl >> 3, c = sl & 7;
        int cs = c ^ (r & 7);
        laneOff[j] = r * KD + cs * 8;
        dstOff[j] = sl * 8;
    }

    const int cg0 = fkg ^ (fr & 7);
    const int fA0 = (wm + fr) * 64 + cg0 * 8;
    const int fB0 = (wn + fr) * 64 + cg0 * 8;

    unsigned khi[16], klo[16];
    #pragma unroll
    for (int sx = 0; sx < 16; ++sx) { khi[sx] = 0u; klo[sx] = 0u; }

    auto stage = [&](int buf, const __bf16* Ab, const __bf16* Bb) {
        #pragma unroll
        for (int j = 0; j < 4; ++j) {
            gld_lds16(Ab + laneOff[j], &sA[buf][dstOff[j]]);
            gld_lds16(Bb + laneOff[j], &sB[buf][dstOff[j]]);
        }
    };

    f32x4 acc[4][4];
    #pragma unroll
    for (int ti = 0; ti < 4; ++ti)
        #pragma unroll
        for (int tj = 0; tj < 4; ++tj) acc[ti][tj] = (f32x4){0.f, 0.f, 0.f, 0.f};

    const __bf16* Abase = A + (size_t)m0 * KD;
    const __bf16* Bbase = B + (size_t)chunk * 1024 * KD;

    stage(0, Abase, Bbase);
    const __bf16* An = Abase + 64;
    const __bf16* Bn = Bbase + 64;

    int cur = 0;
    for (int s = 0; s < 32; ++s) {
        if (s + 1 < 32) {
            stage(cur ^ 1, An, Bn);
            if (((s + 1) & 3) == 3) { An -= 192; Bn += 128 * KD - 192; }
            else                    { An += 64;  Bn += 64; }
            asm volatile("s_waitcnt vmcnt(8)" ::: "memory");
        } else {
            asm volatile("s_waitcnt vmcnt(0)" ::: "memory");
        }
        __builtin_amdgcn_s_barrier();

        #pragma unroll
        for (int kh = 0; kh < 2; ++kh) {
            const __bf16* fB = &sB[cur][fB0 ^ (kh * 32)];
            const __bf16* fA = &sA[cur][fA0 ^ (kh * 32)];
            s16x8 bhf[4];
            #pragma unroll
            for (int tj = 0; tj < 4; ++tj)
                bhf[tj] = *(const s16x8*)(fB + tj * 1024);
            #pragma unroll
            for (int ti = 0; ti < 4; ++ti) {
                s16x8 ahf = *(const s16x8*)(fA + ti * 1024);
                #pragma unroll
                for (int tj = 0; tj < 4; ++tj)
                    acc[ti][tj] = __builtin_amdgcn_mfma_f32_16x16x32_bf16(ahf, bhf[tj], acc[ti][tj], 0, 0, 0);
            }
        }

        if ((s & 3) == 3) {
            const int t = s >> 2;
            #pragma unroll
            for (int sx = 0; sx < 16; ++sx) {
                const int ti = sx >> 2, r = sx & 3;
                #pragma unroll
                for (int tj = 0; tj < 4; ++tj) {
                    unsigned u = __float_as_uint(acc[ti][tj][r]);
                    u ^= ((unsigned)((int)u >> 31)) | 0x80000000u;
                    unsigned key = (u & 0xFFFFFC00u) | (unsigned)(t * 128 + wn + tj * 16 + fr);
                    unsigned h = khi[sx];
                    unsigned mn = min(h, key);
                    khi[sx] = max(h, key);
                    klo[sx] = max(klo[sx], mn);
                    acc[ti][tj][r] = 0.f;
                }
            }
        }
        __builtin_amdgcn_s_barrier();
        cur ^= 1;
    }

    #pragma unroll
    for (int sx = 0; sx < 16; ++sx) {
        unsigned h = khi[sx], lo_ = klo[sx];
        #pragma unroll
        for (int m = 1; m < 16; m <<= 1) {
            unsigned oh = (unsigned)__shfl_xor((int)h, m, 64);
            unsigned ol = (unsigned)__shfl_xor((int)lo_, m, 64);
            unsigned nh = max(h, oh);
            lo_ = max(min(h, oh), max(lo_, ol));
            h = nh;
        }
        if ((l & 15) == 0) {
            int rowlb = wm + (sx >> 2) * 16 + (l >> 4) * 4 + (sx & 3);
            sred[wn >> 6][rowlb] = make_uint2(h, lo_);
        }
    }
    __syncthreads();
    if (tid < 128) {
        uint2 pa = sred[0][tid], pb = sred[1][tid];
        unsigned h = max(pa.x, pb.x);
        unsigned lo_ = max(min(pa.x, pb.x), max(pa.y, pb.y));
        part[(size_t)(m0 + tid) * NCHA + chunk] = make_uint2(h, lo_);
    }
}

// ---------------- exact fp32 rescue over all 32 candidates/row ----------------
// (verbatim R17 — summation order is the exact-argmin arbiter; do not touch)

__global__ void rescue_all_kernel(const float* __restrict__ Zt, const float* __restrict__ cb,
                                  const float* __restrict__ cbrinv, const float* __restrict__ cbsq,
                                  const uint2* __restrict__ part,
                                  int* __restrict__ ridx, float* __restrict__ out_idx) {
    int row = blockIdx.x;
    __shared__ float zrow[KD];
    int tid = threadIdx.x;
    ((float4*)zrow)[tid] = ((const float4*)(Zt + (size_t)row * KD))[tid];
    __syncthreads();

    float tot = 0.f;
    #pragma unroll
    for (int w = 0; w < 4; ++w) {
        float v = zrow[w * 64 + tid];
        float s = v * v;
        #pragma unroll
        for (int m = 32; m; m >>= 1) s += __shfl_xor(s, m, 64);
        tot += s;
    }
    float zrinv = 1.0f / fmaxf(sqrtf(tot), 1e-12f);

    int slot = tid & 31;
    uint2 p = part[(size_t)row * NCHA + (slot >> 1)];
    unsigned key = (slot & 1) ? p.y : p.x;
    int n = (slot >> 1) * 1024 + (int)(key & 1023u);
    float sc = cbrinv[n];
    const float4* c4 = (const float4*)(cb + (size_t)n * KD);
    const float4* z4 = (const float4*)zrow;
    float acc = 0.f;
    #pragma unroll 8
    for (int k = 0; k < KD / 4; ++k) {
        float4 cv = c4[k];
        float4 zv = z4[k];
        acc = fmaf(zv.x, cv.x * sc, acc);
        acc = fmaf(zv.y, cv.y * sc, acc);
        acc = fmaf(zv.z, cv.z * sc, acc);
        acc = fmaf(zv.w, cv.w * sc, acc);
    }
    float s = fmaf(zrinv, acc, -0.5f * cbsq[n]);
    #pragma unroll
    for (int m = 1; m < 32; m <<= 1) {
        float ov = __shfl_xor(s, m, 64); int on = __shfl_xor(n, m, 64);
        if (ov > s || (ov == s && on < n)) { s = ov; n = on; }
    }
    if (tid == 0) { ridx[row] = n; out_idx[row] = (float)n; }
}

// ---------------- gather + z_q output + loss: parallel 16-row tiles ----------
// 512 blocks (2/CU); each wave owns 4 rows; float4 lane loads (coalesced 1KB
// per wave-instr; cb row read is one contiguous 1KB). Per-element zq
// arithmetic unchanged: zq_out = zt + (zq - zt).

__global__ void finalize_kernel(const float* __restrict__ Zt, const float* __restrict__ cb,
                                const int* __restrict__ ridx,
                                float* __restrict__ zq_out, float* __restrict__ lpart) {
    __shared__ float zqt[16][257];
    __shared__ int idxs[16];
    __shared__ float sm[4];
    int b = blockIdx.x, hw0 = blockIdx.y * 16, tid = threadIdx.x;
    if (tid < 16) idxs[tid] = ridx[b * 1024 + hw0 + tid];
    __syncthreads();
    int w = tid >> 6, ln = tid & 63;
    int c0 = ln * 4;
    float dsum = 0.f;
    #pragma unroll
    for (int j = 0; j < 4; ++j) {
        int rl = w * 4 + j;
        int row = b * 1024 + hw0 + rl;
        float4 zt4 = *(const float4*)&Zt[(size_t)row * KD + c0];
        float4 cv  = *(const float4*)&cb[(size_t)idxs[rl] * KD + c0];
        float d0 = cv.x - zt4.x, d1 = cv.y - zt4.y;
        float d2 = cv.z - zt4.z, d3 = cv.w - zt4.w;
        zqt[rl][c0 + 0] = zt4.x + d0;
        zqt[rl][c0 + 1] = zt4.y + d1;
        zqt[rl][c0 + 2] = zt4.z + d2;
        zqt[rl][c0 + 3] = zt4.w + d3;
        dsum = fmaf(d0, d0, dsum);
        dsum = fmaf(d1, d1, dsum);
        dsum = fmaf(d2, d2, dsum);
        dsum = fmaf(d3, d3, dsum);
    }
    #pragma unroll
    for (int m = 32; m; m >>= 1) dsum += __shfl_xor(dsum, m, 64);
    if ((tid & 63) == 0) sm[tid >> 6] = dsum;
    __syncthreads();   // sm visible AND zqt writes visible for write phase
    if (tid == 0) lpart[b * 64 + blockIdx.y] = sm[0] + sm[1] + sm[2] + sm[3];
    // write phase: lanes = hw (coalesced 64B segments per c)
    #pragma unroll
    for (int it = 0; it < 16; ++it) {
        int idx = it * 256 + tid;
        int c = idx >> 4, hwl = idx & 15;
        zq_out[(size_t)b * ZSTRIDE + (size_t)c * HWN + hw0 + hwl] = zqt[hwl][c];
    }
}

__global__ void loss_final_kernel(const float* __restrict__ lpart, float* __restrict__ out) {
    __shared__ float sm[4];
    float s = 0.0f;
    for (int i = threadIdx.x; i < 512; i += 256) s += lpart[i];
    #pragma unroll
    for (int m = 32; m; m >>= 1) s += __shfl_xor(s, m, 64);
    if ((threadIdx.x & 63) == 0) sm[threadIdx.x >> 6] = s;
    __syncthreads();
    if (threadIdx.x == 0) {
        float total = sm[0] + sm[1] + sm[2] + sm[3];
        float m = total * (1.0f / 2097152.0f);
        out[0] = fmaf(0.25f, m, m);
    }
}

// ---------------- launch ----------------

extern "C" void kernel_launch(void* const* d_in, const int* in_sizes, int n_in,
                              void* d_out, int out_size, void* d_ws, size_t ws_size,
                              hipStream_t stream) {
    const float* z  = (const float*)d_in[0];
    const float* cb = (const float*)d_in[1];
    float* out = (float*)d_out;

    float* ws = (float*)d_ws;
    float*  cbrinv = ws;                                 // 16384
    float*  cbsq   = cbrinv + CN;                        // 16384
    int*    ridx   = (int*)(cbsq + CN);                  // 8192
    float*  lpart  = (float*)(ridx + ZM);                // 8192 (512 used)
    uint2*  part   = (uint2*)(lpart + ZM);               // 1 MB (16B-aligned)
    __bf16* Ah     = (__bf16*)(part + (size_t)ZM * NCHA);// 4 MB
    __bf16* Bh     = Ah + (size_t)ZM * KD;               // 8 MB
    float*  Zt     = (float*)(Bh + (size_t)CN * KD);     // 8 MB  (total ~21.4 MB)

    float* out_loss = out;
    float* out_zq   = out + 1;
    float* out_idx  = out + 1 + (size_t)ZM * KD;

    cbprep_kernel<<<CN, 256, 0, stream>>>(cb, cbrinv, cbsq, Bh);
    prep_a_kernel<<<dim3(16, 4, 8), 256, 0, stream>>>(z, Ah, Zt);
    gemm_top2_kernel<<<dim3(64, 16), 256, 0, stream>>>(Ah, Bh, part);
    rescue_all_kernel<<<ZM, 64, 0, stream>>>(Zt, cb, cbrinv, cbsq, part, ridx, out_idx);
    finalize_kernel<<<dim3(8, 64), 256, 0, stream>>>(Zt, cb, ridx, out_zq, lpart);
    loss_final_kernel<<<1, 256, 0, stream>>>(lpart, out_loss);
}

// Round 20
// 179.465 us; speedup vs baseline: 1.1797x; 1.0288x over previous
//
#include <hip/hip_runtime.h>
#include <float.h>
#include <math.h>

#define ZM 8192
#define CN 16384
#define KD 256
#define HWN 1024
#define ZSTRIDE 262144
#define NCHA 16     // 1024 codes per chunk, running top-2 per chunk

typedef short  s16x8  __attribute__((ext_vector_type(8)));
typedef float  f32x4  __attribute__((ext_vector_type(4)));

__device__ inline void gld_lds16(const void* g, void* l) {
    __builtin_amdgcn_global_load_lds((__attribute__((address_space(1))) void*)(g),
                                     (__attribute__((address_space(3))) void*)(l), 16, 0, 0);
}

// ---------------- fused cb stats + bf16 prep (one cb read) ----------------

__global__ void cbprep_kernel(const float* __restrict__ cb, float* __restrict__ cbrinv,
                              float* __restrict__ cbsq, __bf16* __restrict__ Bh) {
    __shared__ float sm[4];
    __shared__ float rsh;
    int n = blockIdx.x;
    float v = cb[(size_t)n * KD + threadIdx.x];
    float s = v * v;
    #pragma unroll
    for (int m = 32; m; m >>= 1) s += __shfl_xor(s, m, 64);
    if ((threadIdx.x & 63) == 0) sm[threadIdx.x >> 6] = s;
    __syncthreads();
    if (threadIdx.x == 0) {
        float t = sm[0] + sm[1] + sm[2] + sm[3];
        float r = 1.0f / fmaxf(sqrtf(t), 1e-12f);
        cbrinv[n] = r;
        cbsq[n] = t * r * r;
        rsh = r;
    }
    __syncthreads();
    Bh[(size_t)n * KD + threadIdx.x] = (__bf16)(v * rsh);
}

// ---------------- z transpose: bf16 Ah + f32 Zt ----------------

__global__ void prep_a_kernel(const float* __restrict__ z, __bf16* __restrict__ Ah,
                              float* __restrict__ Zt) {
    __shared__ float tile[64][65];
    int hw0 = blockIdx.x * 64, c0 = blockIdx.y * 64, b = blockIdx.z;
    int tid = threadIdx.x;
    #pragma unroll
    for (int i = 0; i < 16; ++i) {
        int lin = i * 256 + tid;
        int cl = lin >> 6, hwl = lin & 63;
        tile[cl][hwl] = z[(size_t)b * ZSTRIDE + (size_t)(c0 + cl) * HWN + hw0 + hwl];
    }
    __syncthreads();
    #pragma unroll
    for (int i = 0; i < 16; ++i) {
        int lin = i * 256 + tid;
        int hwl = lin >> 6, cl = lin & 63;
        float v = tile[cl][hwl];
        size_t o = (size_t)(b * 1024 + hw0 + hwl) * KD + c0 + cl;
        Ah[o] = (__bf16)v;
        Zt[o] = v;
    }
}

// ---------------- bf16 MFMA GEMM: BK=64 single-buffer, 4 blocks/CU ----------
// m97-style 2-barrier step; XOR-8 swizzled staging (0 conflicts, R16-verified);
// strength-reduced addressing (R17). LDS 33 KB -> 4 blocks/CU: barrier-drain
// stalls of one block hide under the other 3 blocks' MFMA (m114 mechanism).
// K accumulation order bit-identical to R12/R16/R17.

__global__ __launch_bounds__(256, 2) void gemm_top2_kernel(
    const __bf16* __restrict__ A, const __bf16* __restrict__ B,
    uint2* __restrict__ part)
{
    __shared__ __bf16 sA[128 * 64];     // 16 KB
    __shared__ __bf16 sB[128 * 64];     // 16 KB
    __shared__ uint2 sred[2][128];

    const int tid = threadIdx.x;
    const int l = tid & 63;
    const int wid = tid >> 6;
    const int wm = (wid >> 1) * 64, wn = (wid & 1) * 64;
    const int m0 = blockIdx.x * 128;
    const int chunk = blockIdx.y;
    const int fr = l & 15;
    const int fkg = l >> 4;

    int laneOff[4], dstOff[4];
    #pragma unroll
    for (int j = 0; j < 4; ++j) {
        int sl = j * 256 + tid;
        int r = sl >> 3, c = sl & 7;
        int cs = c ^ (r & 7);
        laneOff[j] = r * KD + cs * 8;
        dstOff[j] = sl * 8;
    }

    const int cg0 = fkg ^ (fr & 7);
    const int fA0 = (wm + fr) * 64 + cg0 * 8;
    const int fB0 = (wn + fr) * 64 + cg0 * 8;

    unsigned khi[16], klo[16];
    #pragma unroll
    for (int sx = 0; sx < 16; ++sx) { khi[sx] = 0u; klo[sx] = 0u; }

    f32x4 acc[4][4];
    #pragma unroll
    for (int ti = 0; ti < 4; ++ti)
        #pragma unroll
        for (int tj = 0; tj < 4; ++tj) acc[ti][tj] = (f32x4){0.f, 0.f, 0.f, 0.f};

    const __bf16* Ac = A + (size_t)m0 * KD;
    const __bf16* Bc = B + (size_t)chunk * 1024 * KD;

    for (int s = 0; s < 32; ++s) {
        #pragma unroll
        for (int j = 0; j < 4; ++j) {
            gld_lds16(Ac + laneOff[j], &sA[dstOff[j]]);
            gld_lds16(Bc + laneOff[j], &sB[dstOff[j]]);
        }
        if ((s & 3) == 3) { Ac -= 192; Bc += 128 * KD - 192; }
        else              { Ac += 64;  Bc += 64; }
        __syncthreads();   // vmcnt(0) drain + all waves arrived

        #pragma unroll
        for (int kh = 0; kh < 2; ++kh) {
            const __bf16* fB = &sB[fB0 ^ (kh * 32)];
            const __bf16* fA = &sA[fA0 ^ (kh * 32)];
            s16x8 bhf[4];
            #pragma unroll
            for (int tj = 0; tj < 4; ++tj)
                bhf[tj] = *(const s16x8*)(fB + tj * 1024);
            #pragma unroll
            for (int ti = 0; ti < 4; ++ti) {
                s16x8 ahf = *(const s16x8*)(fA + ti * 1024);
                #pragma unroll
                for (int tj = 0; tj < 4; ++tj)
                    acc[ti][tj] = __builtin_amdgcn_mfma_f32_16x16x32_bf16(ahf, bhf[tj], acc[ti][tj], 0, 0, 0);
            }
        }

        if ((s & 3) == 3) {
            const int t = s >> 2;
            #pragma unroll
            for (int sx = 0; sx < 16; ++sx) {
                const int ti = sx >> 2, r = sx & 3;
                #pragma unroll
                for (int tj = 0; tj < 4; ++tj) {
                    unsigned u = __float_as_uint(acc[ti][tj][r]);
                    u ^= ((unsigned)((int)u >> 31)) | 0x80000000u;
                    unsigned key = (u & 0xFFFFFC00u) | (unsigned)(t * 128 + wn + tj * 16 + fr);
                    unsigned h = khi[sx];
                    unsigned mn = min(h, key);
                    khi[sx] = max(h, key);
                    klo[sx] = max(klo[sx], mn);
                    acc[ti][tj][r] = 0.f;
                }
            }
        }
        __syncthreads();   // reads done before next step's staging overwrites
    }

    #pragma unroll
    for (int sx = 0; sx < 16; ++sx) {
        unsigned h = khi[sx], lo_ = klo[sx];
        #pragma unroll
        for (int m = 1; m < 16; m <<= 1) {
            unsigned oh = (unsigned)__shfl_xor((int)h, m, 64);
            unsigned ol = (unsigned)__shfl_xor((int)lo_, m, 64);
            unsigned nh = max(h, oh);
            lo_ = max(min(h, oh), max(lo_, ol));
            h = nh;
        }
        if ((l & 15) == 0) {
            int rowlb = wm + (sx >> 2) * 16 + (l >> 4) * 4 + (sx & 3);
            sred[wn >> 6][rowlb] = make_uint2(h, lo_);
        }
    }
    __syncthreads();
    if (tid < 128) {
        uint2 pa = sred[0][tid], pb = sred[1][tid];
        unsigned h = max(pa.x, pb.x);
        unsigned lo_ = max(min(pa.x, pb.x), max(pa.y, pb.y));
        part[(size_t)(m0 + tid) * NCHA + chunk] = make_uint2(h, lo_);
    }
}

// ---------------- exact fp32 rescue over all 32 candidates/row ----------------
// (verbatim — summation order is the exact-argmin arbiter; do not touch)

__global__ void rescue_all_kernel(const float* __restrict__ Zt, const float* __restrict__ cb,
                                  const float* __restrict__ cbrinv, const float* __restrict__ cbsq,
                                  const uint2* __restrict__ part,
                                  int* __restrict__ ridx, float* __restrict__ out_idx) {
    int row = blockIdx.x;
    __shared__ float zrow[KD];
    int tid = threadIdx.x;
    ((float4*)zrow)[tid] = ((const float4*)(Zt + (size_t)row * KD))[tid];
    __syncthreads();

    float tot = 0.f;
    #pragma unroll
    for (int w = 0; w < 4; ++w) {
        float v = zrow[w * 64 + tid];
        float s = v * v;
        #pragma unroll
        for (int m = 32; m; m >>= 1) s += __shfl_xor(s, m, 64);
        tot += s;
    }
    float zrinv = 1.0f / fmaxf(sqrtf(tot), 1e-12f);

    int slot = tid & 31;
    uint2 p = part[(size_t)row * NCHA + (slot >> 1)];
    unsigned key = (slot & 1) ? p.y : p.x;
    int n = (slot >> 1) * 1024 + (int)(key & 1023u);
    float sc = cbrinv[n];
    const float4* c4 = (const float4*)(cb + (size_t)n * KD);
    const float4* z4 = (const float4*)zrow;
    float acc = 0.f;
    #pragma unroll 8
    for (int k = 0; k < KD / 4; ++k) {
        float4 cv = c4[k];
        float4 zv = z4[k];
        acc = fmaf(zv.x, cv.x * sc, acc);
        acc = fmaf(zv.y, cv.y * sc, acc);
        acc = fmaf(zv.z, cv.z * sc, acc);
        acc = fmaf(zv.w, cv.w * sc, acc);
    }
    float s = fmaf(zrinv, acc, -0.5f * cbsq[n]);
    #pragma unroll
    for (int m = 1; m < 32; m <<= 1) {
        float ov = __shfl_xor(s, m, 64); int on = __shfl_xor(n, m, 64);
        if (ov > s || (ov == s && on < n)) { s = ov; n = on; }
    }
    if (tid == 0) { ridx[row] = n; out_idx[row] = (float)n; }
}

// ---------------- gather + z_q output + loss (R19 parallel version) ----------

__global__ void finalize_kernel(const float* __restrict__ Zt, const float* __restrict__ cb,
                                const int* __restrict__ ridx,
                                float* __restrict__ zq_out, float* __restrict__ lpart) {
    __shared__ float zqt[16][257];
    __shared__ int idxs[16];
    __shared__ float sm[4];
    int b = blockIdx.x, hw0 = blockIdx.y * 16, tid = threadIdx.x;
    if (tid < 16) idxs[tid] = ridx[b * 1024 + hw0 + tid];
    __syncthreads();
    int w = tid >> 6, ln = tid & 63;
    int c0 = ln * 4;
    float dsum = 0.f;
    #pragma unroll
    for (int j = 0; j < 4; ++j) {
        int rl = w * 4 + j;
        int row = b * 1024 + hw0 + rl;
        float4 zt4 = *(const float4*)&Zt[(size_t)row * KD + c0];
        float4 cv  = *(const float4*)&cb[(size_t)idxs[rl] * KD + c0];
        float d0 = cv.x - zt4.x, d1 = cv.y - zt4.y;
        float d2 = cv.z - zt4.z, d3 = cv.w - zt4.w;
        zqt[rl][c0 + 0] = zt4.x + d0;
        zqt[rl][c0 + 1] = zt4.y + d1;
        zqt[rl][c0 + 2] = zt4.z + d2;
        zqt[rl][c0 + 3] = zt4.w + d3;
        dsum = fmaf(d0, d0, dsum);
        dsum = fmaf(d1, d1, dsum);
        dsum = fmaf(d2, d2, dsum);
        dsum = fmaf(d3, d3, dsum);
    }
    #pragma unroll
    for (int m = 32; m; m >>= 1) dsum += __shfl_xor(dsum, m, 64);
    if ((tid & 63) == 0) sm[tid >> 6] = dsum;
    __syncthreads();
    if (tid == 0) lpart[b * 64 + blockIdx.y] = sm[0] + sm[1] + sm[2] + sm[3];
    #pragma unroll
    for (int it = 0; it < 16; ++it) {
        int idx = it * 256 + tid;
        int c = idx >> 4, hwl = idx & 15;
        zq_out[(size_t)b * ZSTRIDE + (size_t)c * HWN + hw0 + hwl] = zqt[hwl][c];
    }
}

__global__ void loss_final_kernel(const float* __restrict__ lpart, float* __restrict__ out) {
    __shared__ float sm[4];
    float s = 0.0f;
    for (int i = threadIdx.x; i < 512; i += 256) s += lpart[i];
    #pragma unroll
    for (int m = 32; m; m >>= 1) s += __shfl_xor(s, m, 64);
    if ((threadIdx.x & 63) == 0) sm[threadIdx.x >> 6] = s;
    __syncthreads();
    if (threadIdx.x == 0) {
        float total = sm[0] + sm[1] + sm[2] + sm[3];
        float m = total * (1.0f / 2097152.0f);
        out[0] = fmaf(0.25f, m, m);
    }
}

// ---------------- launch ----------------

extern "C" void kernel_launch(void* const* d_in, const int* in_sizes, int n_in,
                              void* d_out, int out_size, void* d_ws, size_t ws_size,
                              hipStream_t stream) {
    const float* z  = (const float*)d_in[0];
    const float* cb = (const float*)d_in[1];
    float* out = (float*)d_out;

    float* ws = (float*)d_ws;
    float*  cbrinv = ws;                                 // 16384
    float*  cbsq   = cbrinv + CN;                        // 16384
    int*    ridx   = (int*)(cbsq + CN);                  // 8192
    float*  lpart  = (float*)(ridx + ZM);                // 8192 (512 used)
    uint2*  part   = (uint2*)(lpart + ZM);               // 1 MB (16B-aligned)
    __bf16* Ah     = (__bf16*)(part + (size_t)ZM * NCHA);// 4 MB
    __bf16* Bh     = Ah + (size_t)ZM * KD;               // 8 MB
    float*  Zt     = (float*)(Bh + (size_t)CN * KD);     // 8 MB  (total ~21.4 MB)

    float* out_loss = out;
    float* out_zq   = out + 1;
    float* out_idx  = out + 1 + (size_t)ZM * KD;

    cbprep_kernel<<<CN, 256, 0, stream>>>(cb, cbrinv, cbsq, Bh);
    prep_a_kernel<<<dim3(16, 4, 8), 256, 0, stream>>>(z, Ah, Zt);
    gemm_top2_kernel<<<dim3(64, 16), 256, 0, stream>>>(Ah, Bh, part);
    rescue_all_kernel<<<ZM, 64, 0, stream>>>(Zt, cb, cbrinv, cbsq, part, ridx, out_idx);
    finalize_kernel<<<dim3(8, 64), 256, 0, stream>>>(Zt, cb, ridx, out_zq, lpart);
    loss_final_kernel<<<1, 256, 0, stream>>>(lpart, out_loss);
}